// Round 6
// baseline (652.708 us; speedup 1.0000x reference)
//
#include <hip/hip_runtime.h>

typedef __bf16 bf16_t;
typedef __bf16 bf16x8 __attribute__((ext_vector_type(8)));
typedef __bf16 bf16x4 __attribute__((ext_vector_type(4)));
typedef float  f32x4  __attribute__((ext_vector_type(4)));

#define MFMA16(a,b,c) __builtin_amdgcn_mfma_f32_16x16x32_bf16((a),(b),(c),0,0,0)

// LDS plan (bf16 elems), total 20214 -> 40,428 B -> 4 blocks/CU:
//   region [13056]: x [64][200] ->(barrier)-> vT [192][68] ->(barrier)-> attn [64][200]
//                   ->(barrier)-> proj-out f32 [32][196] (two halves)
//   scratch: per-wave [16][64] XOR-swizzled chunk (Q/K roundtrips per-mi band,
//            P[16 queries][64 keys] per-mi). byte ^= (row&7)<<4 makes both the
//            bf16x8 reads and the P reads bank-balanced (stride-64 unswizzled
//            would be 16-way conflicted).
//   bt [1014]: rel-bias table
// Phase 2 computes S^T = mfma(K,Q): softmax key-reduction = 16 in-lane values +
// 2 cross-quad shuffles. Key attrs packed 1 int per key.
// NOTE (round-5 lesson): NO nontemporal hints anywhere — nt on gfx950 bypasses
// L2 line-merging; partial-line-interleaved stores then amplify HBM traffic
// 2.7x (WRITE 345->930 MKiB) and add RMW fills (FETCH 176->646 MKiB).
#define REG_STRIDE 200
#define VT_STRIDE  68
#define REG_ELEMS  13056
#define SC_CHUNK   1024                       // [16][64]
#define SC_OFF     REG_ELEMS                  // 13056
#define BT_OFF     (SC_OFF + 6 * SC_CHUNK)    // 19200
#define SMEM_ELEMS (BT_OFF + 1014)            // 20214 elems = 40428 B
#define FSTRIDE    196                        // f32 proj-out stride

// bf16 weights staged in workspace by prep kernel: qkv_w [576*192] then proj_w [192*192]
#define WPROJ_OFF 110592

__global__ void convert_w_kernel(const float* __restrict__ qkv_w,
                                 const float* __restrict__ proj_w,
                                 bf16_t* __restrict__ wb) {
    const int i = (blockIdx.x * 256 + threadIdx.x) * 4;
    float4 f;
    if (i < WPROJ_OFF) f = *(const float4*)(qkv_w + i);
    else               f = *(const float4*)(proj_w + (i - WPROJ_OFF));
    bf16x4 v;
    v[0] = (bf16_t)f.x; v[1] = (bf16_t)f.y; v[2] = (bf16_t)f.z; v[3] = (bf16_t)f.w;
    *(bf16x4*)(wb + i) = v;
}

// swizzled scratch accessor: row in [0,16), col in [0,64); permutes 16B slots
// within each 128B row -> bank-balanced b128 reads, consistent scalar writes.
__device__ __forceinline__ bf16_t* scp(bf16_t* sc, int row, int col) {
    const int byte = (row * 128 + col * 2) ^ ((row & 7) << 4);
    return (bf16_t*)((char*)sc + byte);
}

// 64x32 GEMM over K=192: A-frags from LDS (row-major, REG_STRIDE), B-frags from
// pre-converted bf16 weight rows w0 (ni=0) / w1 (ni=1), prefetch depth 2.
__device__ __forceinline__ void gemm64x32(const bf16_t* __restrict__ xa,
                                          const bf16_t* __restrict__ w0,
                                          const bf16_t* __restrict__ w1,
                                          f32x4 acc[4][2]) {
    bf16x8 b0 = *(const bf16x8*)(w0);
    bf16x8 b1 = *(const bf16x8*)(w1);
    bf16x8 n0 = *(const bf16x8*)(w0 + 32);
    bf16x8 n1 = *(const bf16x8*)(w1 + 32);
    #pragma unroll
    for (int ks = 0; ks < 6; ++ks) {
        bf16x8 m0, m1;
        if (ks < 4) {
            m0 = *(const bf16x8*)(w0 + (ks + 2) * 32);
            m1 = *(const bf16x8*)(w1 + (ks + 2) * 32);
        }
        __builtin_amdgcn_s_setprio(1);
        #pragma unroll
        for (int mi = 0; mi < 4; ++mi) {
            const bf16x8 afr = *(const bf16x8*)(xa + (mi * 16) * REG_STRIDE + ks * 32);
            acc[mi][0] = MFMA16(afr, b0, acc[mi][0]);
            acc[mi][1] = MFMA16(afr, b1, acc[mi][1]);
        }
        __builtin_amdgcn_s_setprio(0);
        b0 = n0; b1 = n1; n0 = m0; n1 = m1;
    }
}

// acc -> bf16 scratch roundtrip (per-mi 16-row band, swizzled) -> MFMA frag layout
__device__ __forceinline__ void roundtrip(bf16_t* __restrict__ sc, int lanelo, int quad,
                                          const f32x4 acc[4][2], float bias0, float bias1,
                                          bf16x8 outfr[4]) {
    #pragma unroll
    for (int mi = 0; mi < 4; ++mi) {
        #pragma unroll
        for (int r = 0; r < 4; ++r) {
            *scp(sc, quad * 4 + r, lanelo)      = (bf16_t)(acc[mi][0][r] + bias0);
            *scp(sc, quad * 4 + r, 16 + lanelo) = (bf16_t)(acc[mi][1][r] + bias1);
        }
        outfr[mi] = *(const bf16x8*)scp(sc, lanelo, quad * 8);
    }
}

__global__ __launch_bounds__(384, 6)
void swin_fused_kernel(const float* __restrict__ x,
                       const bf16_t* __restrict__ wbuf,
                       const float* __restrict__ qkv_b,
                       const float* __restrict__ proj_b,
                       const float* __restrict__ tbl,
                       float* __restrict__ out)
{
    __shared__ __align__(16) bf16_t smem[SMEM_ELEMS];
    bf16_t* region = smem;
    bf16_t* bt     = smem + BT_OFF;

    const int tid    = threadIdx.x;
    const int lane   = tid & 63;
    const int wave   = tid >> 6;        // == head
    const int lanelo = lane & 15;
    const int quad   = lane >> 4;

    bf16_t* sc = smem + SC_OFF + wave * SC_CHUNK;   // per-wave [16][64] swizzled

    const int blk = blockIdx.x;
    const int b   = blk >> 8;
    const int wh  = (blk >> 4) & 15;
    const int ww  = blk & 15;
    const int rowbase = wh * 7 + 3;     // shifted (i) -> orig (i+3)%112
    const int colbase = ww * 7 + 3;

    // ---- phase 0: bias table + x window -> LDS bf16 (rows 49..63 zeroed) ----
    for (int i = tid; i < 1014; i += 384) bt[i] = (bf16_t)tbl[i];

    {
        const int t0  = tid / 48;              // 384/48 = 8 exactly -> t = t0 + 8*it
        const int c0  = tid - t0 * 48;
        const int cb4 = c0 * 4;
        #pragma unroll
        for (int it = 0; it < 8; ++it) {
            const int t = t0 + it * 8;
            bf16x4 v4;
            if (t < 49) {
                int gr = rowbase + t / 7;  if (gr >= 112) gr -= 112;
                int gc = colbase + t % 7;  if (gc >= 112) gc -= 112;
                const float4 f = *(const float4*)(x + (((long)b * 112 + gr) * 112 + gc) * 192 + cb4);
                v4[0] = (bf16_t)f.x; v4[1] = (bf16_t)f.y;
                v4[2] = (bf16_t)f.z; v4[3] = (bf16_t)f.w;
            } else {
                v4[0] = (bf16_t)0.0f; v4[1] = (bf16_t)0.0f;
                v4[2] = (bf16_t)0.0f; v4[3] = (bf16_t)0.0f;
            }
            *(bf16x4*)(region + t * REG_STRIDE + cb4) = v4;
        }
    }
    __syncthreads();

    // ---- phase 1: per-wave head QKV (each wave computes its own head slice) ----
    const int h = wave;
    const bf16_t* xa = region + lanelo * REG_STRIDE + quad * 8;

    bf16x8 qa[4], kb[4];
    f32x4  vacc[4][2];
    {
        // Q
        {
            const bf16_t* wb = wbuf + (0 * 192 + h * 32) * 192;
            f32x4 acc[4][2] = {};
            gemm64x32(xa, wb + lanelo * 192 + quad * 8, wb + (16 + lanelo) * 192 + quad * 8, acc);
            roundtrip(sc, lanelo, quad, acc,
                      qkv_b[0 * 192 + h * 32 + lanelo], qkv_b[0 * 192 + h * 32 + 16 + lanelo], qa);
        }
        // K
        {
            const bf16_t* wb = wbuf + (1 * 192 + h * 32) * 192;
            f32x4 acc[4][2] = {};
            gemm64x32(xa, wb + lanelo * 192 + quad * 8, wb + (16 + lanelo) * 192 + quad * 8, acc);
            roundtrip(sc, lanelo, quad, acc,
                      qkv_b[1 * 192 + h * 32 + lanelo], qkv_b[1 * 192 + h * 32 + 16 + lanelo], kb);
        }
        // V (keep acc in regs; written to vT after the barrier)
        {
            const bf16_t* wb = wbuf + (2 * 192 + h * 32) * 192;
            f32x4 acc[4][2] = {};
            gemm64x32(xa, wb + lanelo * 192 + quad * 8, wb + (16 + lanelo) * 192 + quad * 8, acc);
            #pragma unroll
            for (int mi = 0; mi < 4; ++mi) {
                vacc[mi][0] = acc[mi][0];
                vacc[mi][1] = acc[mi][1];
            }
        }
    }
    __syncthreads();   // all x reads done -> region becomes vT

    // vT write: region[dim][token], stride 68; wave h owns dims h*32..h*32+31
    {
        const float bias0 = qkv_b[2 * 192 + h * 32 + lanelo];
        const float bias1 = qkv_b[2 * 192 + h * 32 + 16 + lanelo];
        #pragma unroll
        for (int mi = 0; mi < 4; ++mi)
            #pragma unroll
            for (int r = 0; r < 4; ++r) {
                const int tok = quad * 4 + r + 16 * mi;
                region[(h * 32 + lanelo) * VT_STRIDE + tok]      = (bf16_t)(vacc[mi][0][r] + bias0);
                region[(h * 32 + 16 + lanelo) * VT_STRIDE + tok] = (bf16_t)(vacc[mi][1][r] + bias1);
            }
    }

    // ---- phase 2: S^T = K Q^T, in-lane softmax over keys, swizzled P, PV ----
    f32x4 o_[4][2] = {};
    {
        const float scale = 0.17677669529663687f;   // 32^-0.5

        // per-lane key attributes, key = ni*16 + quad*4 + r, packed one int each:
        //   bits 0..11  Ck  = ((6-kh)*13 + (6-kw))*6   (bias-table offset part)
        //   bits 12..15 kid = shift-region id
        //   bit  16     valid (key < 49)
        int kp[4][4];
        #pragma unroll
        for (int ni = 0; ni < 4; ++ni)
            #pragma unroll
            for (int r = 0; r < 4; ++r) {
                const int k  = ni * 16 + quad * 4 + r;
                const int kk = (k < 49) ? k : 48;
                const int kh = kk / 7, kw = kk - kh * 7;
                const int gr = wh * 7 + kh, gc = ww * 7 + kw;
                const int kid = (gr < 105 ? 0 : (gr < 109 ? 1 : 2)) * 3 + (gc < 105 ? 0 : (gc < 109 ? 1 : 2));
                kp[ni][r] = (((6 - kh) * 13 + (6 - kw)) * 6) | (kid << 12) | ((k < 49) << 16);
            }

        // V fragments (own head rows of vT; written by this same wave above)
        const bf16x8 bv00 = *(const bf16x8*)(region + (h * 32 + lanelo) * VT_STRIDE + quad * 8);
        const bf16x8 bv01 = *(const bf16x8*)(region + (h * 32 + 16 + lanelo) * VT_STRIDE + quad * 8);
        const bf16x8 bv10 = *(const bf16x8*)(region + (h * 32 + lanelo) * VT_STRIDE + 32 + quad * 8);
        const bf16x8 bv11 = *(const bf16x8*)(region + (h * 32 + 16 + lanelo) * VT_STRIDE + 32 + quad * 8);

        #pragma unroll
        for (int mi = 0; mi < 4; ++mi) {
            // S^T tile: rows = keys (quad*4+r within ni), cols = queries (lanelo)
            f32x4 st[4];
            __builtin_amdgcn_s_setprio(1);
            #pragma unroll
            for (int ni = 0; ni < 4; ++ni) {
                f32x4 z = {0.f, 0.f, 0.f, 0.f};
                st[ni] = MFMA16(kb[ni], qa[mi], z);
            }
            __builtin_amdgcn_s_setprio(0);

            // query attrs for q = mi*16 + lanelo (once per mi)
            const int q   = mi * 16 + lanelo;
            const int qq  = (q < 49) ? q : 48;
            const int qh  = qq / 7, qw = qq - qh * 7;
            const int gqr = wh * 7 + qh, gqc = ww * 7 + qw;
            const int qid = (gqr < 105 ? 0 : (gqr < 109 ? 1 : 2)) * 3 + (gqc < 105 ? 0 : (gqc < 109 ? 1 : 2));
            const int qoff = (qh * 13 + qw) * 6 + h;

            float sv[4][4];
            float m0 = -1e30f;
            #pragma unroll
            for (int ni = 0; ni < 4; ++ni)
                #pragma unroll
                for (int r = 0; r < 4; ++r) {
                    const int p = kp[ni][r];
                    float v = st[ni][r] * scale + (float)bt[qoff + (p & 0xfff)];
                    if (qid != ((p >> 12) & 0xf)) v -= 100.0f;
                    if (!(p >> 16)) v = -1e30f;
                    sv[ni][r] = v;
                    m0 = fmaxf(m0, v);
                }
            m0 = fmaxf(m0, __shfl_xor(m0, 16));
            m0 = fmaxf(m0, __shfl_xor(m0, 32));
            float sum = 0.f;
            #pragma unroll
            for (int ni = 0; ni < 4; ++ni)
                #pragma unroll
                for (int r = 0; r < 4; ++r) {
                    const float e = __expf(sv[ni][r] - m0);
                    sv[ni][r] = e;
                    sum += e;
                }
            sum += __shfl_xor(sum, 16);
            sum += __shfl_xor(sum, 32);
            const float rinv = 1.0f / sum;

            // P write transposed -> P[query=lanelo][key] row-major (swizzled)
            #pragma unroll
            for (int ni = 0; ni < 4; ++ni)
                #pragma unroll
                for (int r = 0; r < 4; ++r)
                    *scp(sc, lanelo, ni * 16 + quad * 4 + r) = (bf16_t)(sv[ni][r] * rinv);

            // PV (same-wave DS ordering: all P writes precede these reads)
            {
                const bf16x8 ap0 = *(const bf16x8*)scp(sc, lanelo, quad * 8);
                const bf16x8 ap1 = *(const bf16x8*)scp(sc, lanelo, 32 + quad * 8);
                __builtin_amdgcn_s_setprio(1);
                o_[mi][0] = MFMA16(ap0, bv00, o_[mi][0]);
                o_[mi][1] = MFMA16(ap0, bv01, o_[mi][1]);
                o_[mi][0] = MFMA16(ap1, bv10, o_[mi][0]);
                o_[mi][1] = MFMA16(ap1, bv11, o_[mi][1]);
                __builtin_amdgcn_s_setprio(0);
            }
        }
    }
    __syncthreads();   // all vT reads done -> region becomes attn_out

    // attn_out write (C-layout), rows = tokens, stride 200
    #pragma unroll
    for (int mi = 0; mi < 4; ++mi)
        #pragma unroll
        for (int r = 0; r < 4; ++r) {
            const int row = quad * 4 + r + 16 * mi;
            region[row * REG_STRIDE + h * 32 + lanelo]      = (bf16_t)(o_[mi][0][r]);
            region[row * REG_STRIDE + h * 32 + 16 + lanelo] = (bf16_t)(o_[mi][1][r]);
        }
    __syncthreads();

    // ---- phase 3: proj GEMM + bias -> f32 LDS (two 32-token halves) -> full-line
    //      cooperative pixel writes (48 float4 per pixel, contiguous 768 B) ----
    {
        const bf16_t* wb = wbuf + WPROJ_OFF + (wave * 32) * 192;
        f32x4 acc[4][2] = {};
        gemm64x32(xa, wb + lanelo * 192 + quad * 8, wb + (16 + lanelo) * 192 + quad * 8, acc);
        const int o0 = wave * 32 + lanelo;
        const float pb0 = proj_b[o0];
        const float pb1 = proj_b[o0 + 16];
        float* freg = (float*)smem;             // f32 [32][FSTRIDE] view of region
        __syncthreads();                        // all attn-region A-frag reads done
        #pragma unroll
        for (int half = 0; half < 2; ++half) {
            #pragma unroll
            for (int mi = 0; mi < 2; ++mi) {
                const int ami = half * 2 + mi;
                #pragma unroll
                for (int r = 0; r < 4; ++r) {
                    const int row = quad * 4 + r + 16 * mi;   // buffer row = token - 32*half
                    freg[row * FSTRIDE + o0]      = acc[ami][0][r] + pb0;
                    freg[row * FSTRIDE + o0 + 16] = acc[ami][1][r] + pb1;
                }
            }
            __syncthreads();
            const int lim = half ? 816 : 1536;  // (17 or 32 pixels) * 48 float4
            for (int idx = tid; idx < lim; idx += 384) {
                const int t  = idx / 48;
                const int cc = (idx - t * 48) * 4;
                const int tok = half * 32 + t;
                int gr = rowbase + tok / 7;  if (gr >= 112) gr -= 112;
                int gc = colbase + tok % 7;  if (gc >= 112) gc -= 112;
                const float4 v = *(const float4*)(freg + t * FSTRIDE + cc);
                *(float4*)(out + (((long)b * 112 + gr) * 112 + gc) * 192 + cc) = v;
            }
            if (!half) __syncthreads();
        }
    }
}

extern "C" void kernel_launch(void* const* d_in, const int* in_sizes, int n_in,
                              void* d_out, int out_size, void* d_ws, size_t ws_size,
                              hipStream_t stream) {
    const float* x      = (const float*)d_in[0];
    const float* qkv_w  = (const float*)d_in[1];
    const float* qkv_b  = (const float*)d_in[2];
    const float* proj_w = (const float*)d_in[3];
    const float* proj_b = (const float*)d_in[4];
    const float* tbl    = (const float*)d_in[5];
    bf16_t* wbuf = (bf16_t*)d_ws;   // 147456 bf16 = 294,912 B

    convert_w_kernel<<<144, 256, 0, stream>>>(qkv_w, proj_w, wbuf);
    swin_fused_kernel<<<4096, 384, 0, stream>>>(x, wbuf, qkv_b, proj_b, tbl,
                                                (float*)d_out);
}

// Round 7
// 592.365 us; speedup vs baseline: 1.1019x; 1.1019x over previous
//
#include <hip/hip_runtime.h>

typedef __bf16 bf16_t;
typedef __bf16 bf16x8 __attribute__((ext_vector_type(8)));
typedef __bf16 bf16x4 __attribute__((ext_vector_type(4)));
typedef float  f32x4  __attribute__((ext_vector_type(4)));

#define MFMA16(a,b,c) __builtin_amdgcn_mfma_f32_16x16x32_bf16((a),(b),(c),0,0,0)

// LDS plan (bf16 elems), total 20214 -> 40,428 B -> 4 blocks/CU:
//   region [13056]: x [64][200] ->(barrier)-> vT [192][68] ->(barrier)-> attn [64][200]
//                   ->(barrier)-> proj-out f32 [32][196] (two halves)
//   scratch: per-wave [16][64] XOR-swizzled chunk (Q/K roundtrips per-mi band,
//            P[16 queries][64 keys] per-mi).
//   bt [1014]: rel-bias table
// Phase 2 computes S^T = mfma(K,Q): softmax key-reduction = 16 in-lane values +
// 2 cross-quad shuffles. Key attrs packed 1 int per key.
// LAUNCH BOUNDS (round-6 lesson): (384,6) caps unified VGPR+AGPR at 85/wave ->
// phase-2 live set (~105 regs) spills to SCRATCH = GLOBAL memory: FETCH 176->659,
// WRITE 345->930 MKiB, +1.07 GB junk traffic, dur +31%. Keep (384,5) (cap 102).
// (round-5 lesson): no nontemporal hints — they were innocent of the traffic,
// but plain ops proved equal-or-better; L2 line-merging wants default caching.
#define REG_STRIDE 200
#define VT_STRIDE  68
#define REG_ELEMS  13056
#define SC_CHUNK   1024                       // [16][64]
#define SC_OFF     REG_ELEMS                  // 13056
#define BT_OFF     (SC_OFF + 6 * SC_CHUNK)    // 19200
#define SMEM_ELEMS (BT_OFF + 1014)            // 20214 elems = 40428 B
#define FSTRIDE    196                        // f32 proj-out stride

// bf16 weights staged in workspace by prep kernel: qkv_w [576*192] then proj_w [192*192]
#define WPROJ_OFF 110592

__global__ void convert_w_kernel(const float* __restrict__ qkv_w,
                                 const float* __restrict__ proj_w,
                                 bf16_t* __restrict__ wb) {
    const int i = (blockIdx.x * 256 + threadIdx.x) * 4;
    float4 f;
    if (i < WPROJ_OFF) f = *(const float4*)(qkv_w + i);
    else               f = *(const float4*)(proj_w + (i - WPROJ_OFF));
    bf16x4 v;
    v[0] = (bf16_t)f.x; v[1] = (bf16_t)f.y; v[2] = (bf16_t)f.z; v[3] = (bf16_t)f.w;
    *(bf16x4*)(wb + i) = v;
}

// swizzled scratch accessor: row in [0,16), col in [0,64); permutes 16B slots
// within each 128B row -> bank-balanced b128 reads, consistent scalar writes.
__device__ __forceinline__ bf16_t* scp(bf16_t* sc, int row, int col) {
    const int byte = (row * 128 + col * 2) ^ ((row & 7) << 4);
    return (bf16_t*)((char*)sc + byte);
}

// 64x32 GEMM over K=192: A-frags from LDS (row-major, REG_STRIDE), B-frags from
// pre-converted bf16 weight rows w0 (ni=0) / w1 (ni=1), prefetch depth 2.
__device__ __forceinline__ void gemm64x32(const bf16_t* __restrict__ xa,
                                          const bf16_t* __restrict__ w0,
                                          const bf16_t* __restrict__ w1,
                                          f32x4 acc[4][2]) {
    bf16x8 b0 = *(const bf16x8*)(w0);
    bf16x8 b1 = *(const bf16x8*)(w1);
    bf16x8 n0 = *(const bf16x8*)(w0 + 32);
    bf16x8 n1 = *(const bf16x8*)(w1 + 32);
    #pragma unroll
    for (int ks = 0; ks < 6; ++ks) {
        bf16x8 m0, m1;
        if (ks < 4) {
            m0 = *(const bf16x8*)(w0 + (ks + 2) * 32);
            m1 = *(const bf16x8*)(w1 + (ks + 2) * 32);
        }
        __builtin_amdgcn_s_setprio(1);
        #pragma unroll
        for (int mi = 0; mi < 4; ++mi) {
            const bf16x8 afr = *(const bf16x8*)(xa + (mi * 16) * REG_STRIDE + ks * 32);
            acc[mi][0] = MFMA16(afr, b0, acc[mi][0]);
            acc[mi][1] = MFMA16(afr, b1, acc[mi][1]);
        }
        __builtin_amdgcn_s_setprio(0);
        b0 = n0; b1 = n1; n0 = m0; n1 = m1;
    }
}

// acc -> bf16 scratch roundtrip (per-mi 16-row band, swizzled) -> MFMA frag layout
__device__ __forceinline__ void roundtrip(bf16_t* __restrict__ sc, int lanelo, int quad,
                                          const f32x4 acc[4][2], float bias0, float bias1,
                                          bf16x8 outfr[4]) {
    #pragma unroll
    for (int mi = 0; mi < 4; ++mi) {
        #pragma unroll
        for (int r = 0; r < 4; ++r) {
            *scp(sc, quad * 4 + r, lanelo)      = (bf16_t)(acc[mi][0][r] + bias0);
            *scp(sc, quad * 4 + r, 16 + lanelo) = (bf16_t)(acc[mi][1][r] + bias1);
        }
        outfr[mi] = *(const bf16x8*)scp(sc, lanelo, quad * 8);
    }
}

__global__ __launch_bounds__(384, 5)
void swin_fused_kernel(const float* __restrict__ x,
                       const bf16_t* __restrict__ wbuf,
                       const float* __restrict__ qkv_b,
                       const float* __restrict__ proj_b,
                       const float* __restrict__ tbl,
                       float* __restrict__ out)
{
    __shared__ __align__(16) bf16_t smem[SMEM_ELEMS];
    bf16_t* region = smem;
    bf16_t* bt     = smem + BT_OFF;

    const int tid    = threadIdx.x;
    const int lane   = tid & 63;
    const int wave   = tid >> 6;        // == head
    const int lanelo = lane & 15;
    const int quad   = lane >> 4;

    bf16_t* sc = smem + SC_OFF + wave * SC_CHUNK;   // per-wave [16][64] swizzled

    const int blk = blockIdx.x;
    const int b   = blk >> 8;
    const int wh  = (blk >> 4) & 15;
    const int ww  = blk & 15;
    const int rowbase = wh * 7 + 3;     // shifted (i) -> orig (i+3)%112
    const int colbase = ww * 7 + 3;

    // ---- phase 0: bias table + x window -> LDS bf16 (rows 49..63 zeroed) ----
    for (int i = tid; i < 1014; i += 384) bt[i] = (bf16_t)tbl[i];

    {
        const int t0  = tid / 48;              // 384/48 = 8 exactly -> t = t0 + 8*it
        const int c0  = tid - t0 * 48;
        const int cb4 = c0 * 4;
        #pragma unroll
        for (int it = 0; it < 8; ++it) {
            const int t = t0 + it * 8;
            bf16x4 v4;
            if (t < 49) {
                int gr = rowbase + t / 7;  if (gr >= 112) gr -= 112;
                int gc = colbase + t % 7;  if (gc >= 112) gc -= 112;
                const float4 f = *(const float4*)(x + (((long)b * 112 + gr) * 112 + gc) * 192 + cb4);
                v4[0] = (bf16_t)f.x; v4[1] = (bf16_t)f.y;
                v4[2] = (bf16_t)f.z; v4[3] = (bf16_t)f.w;
            } else {
                v4[0] = (bf16_t)0.0f; v4[1] = (bf16_t)0.0f;
                v4[2] = (bf16_t)0.0f; v4[3] = (bf16_t)0.0f;
            }
            *(bf16x4*)(region + t * REG_STRIDE + cb4) = v4;
        }
    }
    __syncthreads();

    // ---- phase 1: per-wave head QKV (each wave computes its own head slice) ----
    const int h = wave;
    const bf16_t* xa = region + lanelo * REG_STRIDE + quad * 8;

    bf16x8 qa[4], kb[4];
    f32x4  vacc[4][2];
    {
        // Q
        {
            const bf16_t* wb = wbuf + (0 * 192 + h * 32) * 192;
            f32x4 acc[4][2] = {};
            gemm64x32(xa, wb + lanelo * 192 + quad * 8, wb + (16 + lanelo) * 192 + quad * 8, acc);
            roundtrip(sc, lanelo, quad, acc,
                      qkv_b[0 * 192 + h * 32 + lanelo], qkv_b[0 * 192 + h * 32 + 16 + lanelo], qa);
        }
        // K
        {
            const bf16_t* wb = wbuf + (1 * 192 + h * 32) * 192;
            f32x4 acc[4][2] = {};
            gemm64x32(xa, wb + lanelo * 192 + quad * 8, wb + (16 + lanelo) * 192 + quad * 8, acc);
            roundtrip(sc, lanelo, quad, acc,
                      qkv_b[1 * 192 + h * 32 + lanelo], qkv_b[1 * 192 + h * 32 + 16 + lanelo], kb);
        }
        // V (keep acc in regs; written to vT after the barrier)
        {
            const bf16_t* wb = wbuf + (2 * 192 + h * 32) * 192;
            f32x4 acc[4][2] = {};
            gemm64x32(xa, wb + lanelo * 192 + quad * 8, wb + (16 + lanelo) * 192 + quad * 8, acc);
            #pragma unroll
            for (int mi = 0; mi < 4; ++mi) {
                vacc[mi][0] = acc[mi][0];
                vacc[mi][1] = acc[mi][1];
            }
        }
    }
    __syncthreads();   // all x reads done -> region becomes vT

    // vT write: region[dim][token], stride 68; wave h owns dims h*32..h*32+31
    {
        const float bias0 = qkv_b[2 * 192 + h * 32 + lanelo];
        const float bias1 = qkv_b[2 * 192 + h * 32 + 16 + lanelo];
        #pragma unroll
        for (int mi = 0; mi < 4; ++mi)
            #pragma unroll
            for (int r = 0; r < 4; ++r) {
                const int tok = quad * 4 + r + 16 * mi;
                region[(h * 32 + lanelo) * VT_STRIDE + tok]      = (bf16_t)(vacc[mi][0][r] + bias0);
                region[(h * 32 + 16 + lanelo) * VT_STRIDE + tok] = (bf16_t)(vacc[mi][1][r] + bias1);
            }
    }

    // ---- phase 2: S^T = K Q^T, in-lane softmax over keys, swizzled P, PV ----
    f32x4 o_[4][2] = {};
    {
        const float scale = 0.17677669529663687f;   // 32^-0.5

        // per-lane key attributes, key = ni*16 + quad*4 + r, packed one int each:
        //   bits 0..11  Ck  = ((6-kh)*13 + (6-kw))*6   (bias-table offset part)
        //   bits 12..15 kid = shift-region id
        //   bit  16     valid (key < 49)
        int kp[4][4];
        #pragma unroll
        for (int ni = 0; ni < 4; ++ni)
            #pragma unroll
            for (int r = 0; r < 4; ++r) {
                const int k  = ni * 16 + quad * 4 + r;
                const int kk = (k < 49) ? k : 48;
                const int kh = kk / 7, kw = kk - kh * 7;
                const int gr = wh * 7 + kh, gc = ww * 7 + kw;
                const int kid = (gr < 105 ? 0 : (gr < 109 ? 1 : 2)) * 3 + (gc < 105 ? 0 : (gc < 109 ? 1 : 2));
                kp[ni][r] = (((6 - kh) * 13 + (6 - kw)) * 6) | (kid << 12) | ((k < 49) << 16);
            }

        // V fragments (own head rows of vT; written by this same wave above)
        const bf16x8 bv00 = *(const bf16x8*)(region + (h * 32 + lanelo) * VT_STRIDE + quad * 8);
        const bf16x8 bv01 = *(const bf16x8*)(region + (h * 32 + 16 + lanelo) * VT_STRIDE + quad * 8);
        const bf16x8 bv10 = *(const bf16x8*)(region + (h * 32 + lanelo) * VT_STRIDE + 32 + quad * 8);
        const bf16x8 bv11 = *(const bf16x8*)(region + (h * 32 + 16 + lanelo) * VT_STRIDE + 32 + quad * 8);

        #pragma unroll
        for (int mi = 0; mi < 4; ++mi) {
            // S^T tile: rows = keys (quad*4+r within ni), cols = queries (lanelo)
            f32x4 st[4];
            __builtin_amdgcn_s_setprio(1);
            #pragma unroll
            for (int ni = 0; ni < 4; ++ni) {
                f32x4 z = {0.f, 0.f, 0.f, 0.f};
                st[ni] = MFMA16(kb[ni], qa[mi], z);
            }
            __builtin_amdgcn_s_setprio(0);

            // query attrs for q = mi*16 + lanelo (once per mi)
            const int q   = mi * 16 + lanelo;
            const int qq  = (q < 49) ? q : 48;
            const int qh  = qq / 7, qw = qq - qh * 7;
            const int gqr = wh * 7 + qh, gqc = ww * 7 + qw;
            const int qid = (gqr < 105 ? 0 : (gqr < 109 ? 1 : 2)) * 3 + (gqc < 105 ? 0 : (gqc < 109 ? 1 : 2));
            const int qoff = (qh * 13 + qw) * 6 + h;

            float sv[4][4];
            float m0 = -1e30f;
            #pragma unroll
            for (int ni = 0; ni < 4; ++ni)
                #pragma unroll
                for (int r = 0; r < 4; ++r) {
                    const int p = kp[ni][r];
                    float v = st[ni][r] * scale + (float)bt[qoff + (p & 0xfff)];
                    if (qid != ((p >> 12) & 0xf)) v -= 100.0f;
                    if (!(p >> 16)) v = -1e30f;
                    sv[ni][r] = v;
                    m0 = fmaxf(m0, v);
                }
            m0 = fmaxf(m0, __shfl_xor(m0, 16));
            m0 = fmaxf(m0, __shfl_xor(m0, 32));
            float sum = 0.f;
            #pragma unroll
            for (int ni = 0; ni < 4; ++ni)
                #pragma unroll
                for (int r = 0; r < 4; ++r) {
                    const float e = __expf(sv[ni][r] - m0);
                    sv[ni][r] = e;
                    sum += e;
                }
            sum += __shfl_xor(sum, 16);
            sum += __shfl_xor(sum, 32);
            const float rinv = 1.0f / sum;

            // P write transposed -> P[query=lanelo][key] row-major (swizzled)
            #pragma unroll
            for (int ni = 0; ni < 4; ++ni)
                #pragma unroll
                for (int r = 0; r < 4; ++r)
                    *scp(sc, lanelo, ni * 16 + quad * 4 + r) = (bf16_t)(sv[ni][r] * rinv);

            // PV (same-wave DS ordering: all P writes precede these reads)
            {
                const bf16x8 ap0 = *(const bf16x8*)scp(sc, lanelo, quad * 8);
                const bf16x8 ap1 = *(const bf16x8*)scp(sc, lanelo, 32 + quad * 8);
                __builtin_amdgcn_s_setprio(1);
                o_[mi][0] = MFMA16(ap0, bv00, o_[mi][0]);
                o_[mi][1] = MFMA16(ap0, bv01, o_[mi][1]);
                o_[mi][0] = MFMA16(ap1, bv10, o_[mi][0]);
                o_[mi][1] = MFMA16(ap1, bv11, o_[mi][1]);
                __builtin_amdgcn_s_setprio(0);
            }
        }
    }
    __syncthreads();   // all vT reads done -> region becomes attn_out

    // attn_out write (C-layout), rows = tokens, stride 200
    #pragma unroll
    for (int mi = 0; mi < 4; ++mi)
        #pragma unroll
        for (int r = 0; r < 4; ++r) {
            const int row = quad * 4 + r + 16 * mi;
            region[row * REG_STRIDE + h * 32 + lanelo]      = (bf16_t)(o_[mi][0][r]);
            region[row * REG_STRIDE + h * 32 + 16 + lanelo] = (bf16_t)(o_[mi][1][r]);
        }
    __syncthreads();

    // ---- phase 3: proj GEMM + bias -> f32 LDS (two 32-token halves) -> full-line
    //      cooperative pixel writes (48 float4 per pixel, contiguous 768 B) ----
    {
        const bf16_t* wb = wbuf + WPROJ_OFF + (wave * 32) * 192;
        f32x4 acc[4][2] = {};
        gemm64x32(xa, wb + lanelo * 192 + quad * 8, wb + (16 + lanelo) * 192 + quad * 8, acc);
        const int o0 = wave * 32 + lanelo;
        const float pb0 = proj_b[o0];
        const float pb1 = proj_b[o0 + 16];
        float* freg = (float*)smem;             // f32 [32][FSTRIDE] view of region
        __syncthreads();                        // all attn-region A-frag reads done
        #pragma unroll
        for (int half = 0; half < 2; ++half) {
            #pragma unroll
            for (int mi = 0; mi < 2; ++mi) {
                const int ami = half * 2 + mi;
                #pragma unroll
                for (int r = 0; r < 4; ++r) {
                    const int row = quad * 4 + r + 16 * mi;   // buffer row = token - 32*half
                    freg[row * FSTRIDE + o0]      = acc[ami][0][r] + pb0;
                    freg[row * FSTRIDE + o0 + 16] = acc[ami][1][r] + pb1;
                }
            }
            __syncthreads();
            const int lim = half ? 816 : 1536;  // (17 or 32 pixels) * 48 float4
            for (int idx = tid; idx < lim; idx += 384) {
                const int t  = idx / 48;
                const int cc = (idx - t * 48) * 4;
                const int tok = half * 32 + t;
                int gr = rowbase + tok / 7;  if (gr >= 112) gr -= 112;
                int gc = colbase + tok % 7;  if (gc >= 112) gc -= 112;
                const float4 v = *(const float4*)(freg + t * FSTRIDE + cc);
                *(float4*)(out + (((long)b * 112 + gr) * 112 + gc) * 192 + cc) = v;
            }
            if (!half) __syncthreads();
        }
    }
}

extern "C" void kernel_launch(void* const* d_in, const int* in_sizes, int n_in,
                              void* d_out, int out_size, void* d_ws, size_t ws_size,
                              hipStream_t stream) {
    const float* x      = (const float*)d_in[0];
    const float* qkv_w  = (const float*)d_in[1];
    const float* qkv_b  = (const float*)d_in[2];
    const float* proj_w = (const float*)d_in[3];
    const float* proj_b = (const float*)d_in[4];
    const float* tbl    = (const float*)d_in[5];
    bf16_t* wbuf = (bf16_t*)d_ws;   // 147456 bf16 = 294,912 B

    convert_w_kernel<<<144, 256, 0, stream>>>(qkv_w, proj_w, wbuf);
    swin_fused_kernel<<<4096, 384, 0, stream>>>(x, wbuf, qkv_b, proj_b, tbl,
                                                (float*)d_out);
}

// Round 8
// 529.667 us; speedup vs baseline: 1.2323x; 1.1184x over previous
//
#include <hip/hip_runtime.h>

typedef __bf16 bf16_t;
typedef __bf16 bf16x8 __attribute__((ext_vector_type(8)));
typedef __bf16 bf16x4 __attribute__((ext_vector_type(4)));
typedef float  f32x4  __attribute__((ext_vector_type(4)));

#define MFMA16(a,b,c) __builtin_amdgcn_mfma_f32_16x16x32_bf16((a),(b),(c),0,0,0)

// LDS plan (bf16 elems), total 17910 -> 35,820 B (round-3 proven layout):
//   region [13056]: x [64][200] ->(barrier)-> vT [192][68] ->(barrier)-> attn [64][200]
//                   ->(barrier)-> proj-out f32 [32][196] (two halves)
//   scratch: per-wave [16][40] chunk (Q/K/P roundtrips, one 16-row band at a time;
//            same-wave DS ordering makes barrier-free reuse safe)
//   bt [1014]: rel-bias table
// REGISTER DISCIPLINE (rounds 4-7 lesson): occupancy is reg-bound at the
// __launch_bounds__ cap (unified VGPR+AGPR); phase-2 must fit under 102 or it
// spills to scratch=global (r7: +0.7 GB traffic, +16% dur). This phase 2 is
// round-3's (proven fit) minus kvalid/kid pressure: validity is static
// (ni<3 always valid; ni==3 -> lanelo==0), and shift-mask kid/idq math runs
// only for edge windows (wh==15||ww==15, 31/256 blocks) under a uniform branch.
// Scale 1/sqrt(32) folded into the Q roundtrip (pre-scaled Q).
// (round-5/6 lesson): no nontemporal hints.
#define REG_STRIDE 200
#define VT_STRIDE  68
#define REG_ELEMS  13056
#define SC_STRIDE  40
#define SC_CHUNK   640                        // [16][40]
#define BT_OFF     (REG_ELEMS + 6 * SC_CHUNK) // 16896
#define SMEM_ELEMS (BT_OFF + 1014)            // 17910 elems = 35820 B
#define FSTRIDE    196                        // f32 proj-out stride

// bf16 weights staged in workspace by prep kernel: qkv_w [576*192] then proj_w [192*192]
#define WPROJ_OFF 110592

__global__ void convert_w_kernel(const float* __restrict__ qkv_w,
                                 const float* __restrict__ proj_w,
                                 bf16_t* __restrict__ wb) {
    const int i = (blockIdx.x * 256 + threadIdx.x) * 4;
    float4 f;
    if (i < WPROJ_OFF) f = *(const float4*)(qkv_w + i);
    else               f = *(const float4*)(proj_w + (i - WPROJ_OFF));
    bf16x4 v;
    v[0] = (bf16_t)f.x; v[1] = (bf16_t)f.y; v[2] = (bf16_t)f.z; v[3] = (bf16_t)f.w;
    *(bf16x4*)(wb + i) = v;
}

// 64x32 GEMM over K=192: A-frags from LDS (row-major, REG_STRIDE), B-frags from
// pre-converted bf16 weight rows w0 (ni=0) / w1 (ni=1), prefetch depth 2.
__device__ __forceinline__ void gemm64x32(const bf16_t* __restrict__ xa,
                                          const bf16_t* __restrict__ w0,
                                          const bf16_t* __restrict__ w1,
                                          f32x4 acc[4][2]) {
    bf16x8 b0 = *(const bf16x8*)(w0);
    bf16x8 b1 = *(const bf16x8*)(w1);
    bf16x8 n0 = *(const bf16x8*)(w0 + 32);
    bf16x8 n1 = *(const bf16x8*)(w1 + 32);
    #pragma unroll
    for (int ks = 0; ks < 6; ++ks) {
        bf16x8 m0, m1;
        if (ks < 4) {
            m0 = *(const bf16x8*)(w0 + (ks + 2) * 32);
            m1 = *(const bf16x8*)(w1 + (ks + 2) * 32);
        }
        __builtin_amdgcn_s_setprio(1);
        #pragma unroll
        for (int mi = 0; mi < 4; ++mi) {
            const bf16x8 afr = *(const bf16x8*)(xa + (mi * 16) * REG_STRIDE + ks * 32);
            acc[mi][0] = MFMA16(afr, b0, acc[mi][0]);
            acc[mi][1] = MFMA16(afr, b1, acc[mi][1]);
        }
        __builtin_amdgcn_s_setprio(0);
        b0 = n0; b1 = n1; n0 = m0; n1 = m1;
    }
}

__global__ __launch_bounds__(384, 5)
void swin_fused_kernel(const float* __restrict__ x,
                       const bf16_t* __restrict__ wbuf,
                       const float* __restrict__ qkv_b,
                       const float* __restrict__ proj_b,
                       const float* __restrict__ tbl,
                       float* __restrict__ out)
{
    __shared__ __align__(16) bf16_t smem[SMEM_ELEMS];
    bf16_t* region = smem;
    bf16_t* bt     = smem + BT_OFF;

    const int tid    = threadIdx.x;
    const int lane   = tid & 63;
    const int wave   = tid >> 6;        // == head
    const int lanelo = lane & 15;
    const int quad   = lane >> 4;

    bf16_t* sc = smem + REG_ELEMS + wave * SC_CHUNK;   // per-wave [16][40]

    const int blk = blockIdx.x;
    const int b   = blk >> 8;
    const int wh  = (blk >> 4) & 15;
    const int ww  = blk & 15;
    const int rowbase = wh * 7 + 3;     // shifted (i) -> orig (i+3)%112
    const int colbase = ww * 7 + 3;

    // ---- phase 0: bias table + x window -> LDS bf16 (rows 49..63 zeroed) ----
    for (int i = tid; i < 1014; i += 384) bt[i] = (bf16_t)tbl[i];

    for (int idx = tid; idx < 64 * 48; idx += 384) {
        const int t  = idx / 48;
        const int c4 = (idx - t * 48) * 4;
        bf16x4 v4;
        if (t < 49) {
            int gr = rowbase + t / 7;  if (gr >= 112) gr -= 112;
            int gc = colbase + t % 7;  if (gc >= 112) gc -= 112;
            const float4 f = *(const float4*)(x + (((long)b * 112 + gr) * 112 + gc) * 192 + c4);
            v4[0] = (bf16_t)f.x; v4[1] = (bf16_t)f.y;
            v4[2] = (bf16_t)f.z; v4[3] = (bf16_t)f.w;
        } else {
            v4[0] = (bf16_t)0.0f; v4[1] = (bf16_t)0.0f;
            v4[2] = (bf16_t)0.0f; v4[3] = (bf16_t)0.0f;
        }
        *(bf16x4*)(region + t * REG_STRIDE + c4) = v4;
    }
    __syncthreads();

    // ---- phase 1: per-wave head QKV (each wave computes its own head slice) ----
    const int h = wave;
    const bf16_t* xa = region + lanelo * REG_STRIDE + quad * 8;
    const float qscale = 0.17677669529663687f;   // 32^-0.5, folded into Q

    bf16x8 qa[4], kb[4];
    f32x4  vacc[4][2];
    {
        // Q (pre-scaled)
        {
            const bf16_t* wb = wbuf + (0 * 192 + h * 32) * 192;
            f32x4 acc[4][2] = {};
            gemm64x32(xa, wb + lanelo * 192 + quad * 8, wb + (16 + lanelo) * 192 + quad * 8, acc);
            const float b0q = qkv_b[0 * 192 + h * 32 + lanelo] * qscale;
            const float b1q = qkv_b[0 * 192 + h * 32 + 16 + lanelo] * qscale;
            #pragma unroll
            for (int mi = 0; mi < 4; ++mi) {
                #pragma unroll
                for (int r = 0; r < 4; ++r) {
                    sc[(quad * 4 + r) * SC_STRIDE + lanelo]      = (bf16_t)fmaf(acc[mi][0][r], qscale, b0q);
                    sc[(quad * 4 + r) * SC_STRIDE + 16 + lanelo] = (bf16_t)fmaf(acc[mi][1][r], qscale, b1q);
                }
                qa[mi] = *(const bf16x8*)(sc + lanelo * SC_STRIDE + quad * 8);
            }
        }
        // K
        {
            const bf16_t* wb = wbuf + (1 * 192 + h * 32) * 192;
            f32x4 acc[4][2] = {};
            gemm64x32(xa, wb + lanelo * 192 + quad * 8, wb + (16 + lanelo) * 192 + quad * 8, acc);
            const float bias0 = qkv_b[1 * 192 + h * 32 + lanelo];
            const float bias1 = qkv_b[1 * 192 + h * 32 + 16 + lanelo];
            #pragma unroll
            for (int mi = 0; mi < 4; ++mi) {
                #pragma unroll
                for (int r = 0; r < 4; ++r) {
                    sc[(quad * 4 + r) * SC_STRIDE + lanelo]      = (bf16_t)(acc[mi][0][r] + bias0);
                    sc[(quad * 4 + r) * SC_STRIDE + 16 + lanelo] = (bf16_t)(acc[mi][1][r] + bias1);
                }
                kb[mi] = *(const bf16x8*)(sc + lanelo * SC_STRIDE + quad * 8);
            }
        }
        // V (keep acc in regs; written to vT after the barrier)
        {
            const bf16_t* wb = wbuf + (2 * 192 + h * 32) * 192;
            f32x4 acc[4][2] = {};
            gemm64x32(xa, wb + lanelo * 192 + quad * 8, wb + (16 + lanelo) * 192 + quad * 8, acc);
            #pragma unroll
            for (int mi = 0; mi < 4; ++mi) {
                vacc[mi][0] = acc[mi][0];
                vacc[mi][1] = acc[mi][1];
            }
        }
    }
    __syncthreads();   // all x reads done -> region becomes vT

    // vT write: region[dim][token], stride 68; wave h owns dims h*32..h*32+31
    {
        const float bias0 = qkv_b[2 * 192 + h * 32 + lanelo];
        const float bias1 = qkv_b[2 * 192 + h * 32 + 16 + lanelo];
        #pragma unroll
        for (int mi = 0; mi < 4; ++mi)
            #pragma unroll
            for (int r = 0; r < 4; ++r) {
                const int tok = quad * 4 + r + 16 * mi;
                region[(h * 32 + lanelo) * VT_STRIDE + tok]      = (bf16_t)(vacc[mi][0][r] + bias0);
                region[(h * 32 + 16 + lanelo) * VT_STRIDE + tok] = (bf16_t)(vacc[mi][1][r] + bias1);
            }
    }

    // ---- phase 2: S = Q K^T (pre-scaled), bias+mask+softmax, P roundtrip, PV ----
    f32x4 o_[4][2] = {};
    {
        const bool interior = (wh < 15) && (ww < 15);   // wave-uniform

        // per-lane key-column attributes per ni tile (col = ni*16 + lanelo).
        // Validity is static: ni<3 always valid; ni==3 valid iff lanelo==0.
        int kch[4], kcw[4], kid[4] = {0, 0, 0, 0};
        #pragma unroll
        for (int ni = 0; ni < 4; ++ni) {
            const int col = ni * 16 + lanelo;
            const int cc = (col < 49) ? col : 48;
            kch[ni] = cc / 7; kcw[ni] = cc - kch[ni] * 7;
        }
        if (!interior) {
            #pragma unroll
            for (int ni = 0; ni < 4; ++ni) {
                const int gr = wh * 7 + kch[ni], gc = ww * 7 + kcw[ni];
                kid[ni] = (gr < 105 ? 0 : (gr < 109 ? 1 : 2)) * 3 + (gc < 105 ? 0 : (gc < 109 ? 1 : 2));
            }
        }

        // V fragments (own head rows of vT; written by this same wave above)
        const bf16x8 bv00 = *(const bf16x8*)(region + (h * 32 + lanelo) * VT_STRIDE + quad * 8);
        const bf16x8 bv01 = *(const bf16x8*)(region + (h * 32 + 16 + lanelo) * VT_STRIDE + quad * 8);
        const bf16x8 bv10 = *(const bf16x8*)(region + (h * 32 + lanelo) * VT_STRIDE + 32 + quad * 8);
        const bf16x8 bv11 = *(const bf16x8*)(region + (h * 32 + 16 + lanelo) * VT_STRIDE + 32 + quad * 8);

        #pragma unroll
        for (int mi = 0; mi < 4; ++mi) {
            f32x4 s[4];
            __builtin_amdgcn_s_setprio(1);
            #pragma unroll
            for (int ni = 0; ni < 4; ++ni) {
                f32x4 z = {0.f, 0.f, 0.f, 0.f};
                s[ni] = MFMA16(qa[mi], kb[ni], z);
            }
            __builtin_amdgcn_s_setprio(0);
            #pragma unroll
            for (int r = 0; r < 4; ++r) {
                const int row = mi * 16 + quad * 4 + r;
                const int rq  = (row < 49) ? row : 48;
                const int rh  = rq / 7, rw = rq - (rq / 7) * 7;
                int idq = 0;
                if (!interior) {
                    const int gqr = wh * 7 + rh, gqc = ww * 7 + rw;
                    idq = (gqr < 105 ? 0 : (gqr < 109 ? 1 : 2)) * 3 + (gqc < 105 ? 0 : (gqc < 109 ? 1 : 2));
                }
                #pragma unroll
                for (int ni = 0; ni < 4; ++ni) {
                    const int bidx = ((rh - kch[ni] + 6) * 13 + (rw - kcw[ni] + 6)) * 6 + h;
                    float v = s[ni][r] + (float)bt[bidx];
                    if (!interior && (idq != kid[ni])) v -= 100.0f;
                    if (ni == 3) v = (lanelo == 0) ? v : -1e30f;   // static validity
                    s[ni][r] = v;
                }
                float m0 = fmaxf(fmaxf(s[0][r], s[1][r]), fmaxf(s[2][r], s[3][r]));
                m0 = fmaxf(m0, __shfl_xor(m0, 1));
                m0 = fmaxf(m0, __shfl_xor(m0, 2));
                m0 = fmaxf(m0, __shfl_xor(m0, 4));
                m0 = fmaxf(m0, __shfl_xor(m0, 8));
                float sum = 0.f;
                #pragma unroll
                for (int ni = 0; ni < 4; ++ni) {
                    const float e = __expf(s[ni][r] - m0);
                    s[ni][r] = e;
                    sum += e;
                }
                sum += __shfl_xor(sum, 1);
                sum += __shfl_xor(sum, 2);
                sum += __shfl_xor(sum, 4);
                sum += __shfl_xor(sum, 8);
                const float rinv = 1.0f / sum;
                // P cols 0..31 (ni=0,1) -> chunk now; keep ni=2,3 normalized in regs
                sc[(quad * 4 + r) * SC_STRIDE + lanelo]      = (bf16_t)(s[0][r] * rinv);
                sc[(quad * 4 + r) * SC_STRIDE + 16 + lanelo] = (bf16_t)(s[1][r] * rinv);
                s[2][r] *= rinv;
                s[3][r] *= rinv;
            }
            {   // PV ks=0
                const bf16x8 ap = *(const bf16x8*)(sc + lanelo * SC_STRIDE + quad * 8);
                __builtin_amdgcn_s_setprio(1);
                o_[mi][0] = MFMA16(ap, bv00, o_[mi][0]);
                o_[mi][1] = MFMA16(ap, bv01, o_[mi][1]);
                __builtin_amdgcn_s_setprio(0);
            }
            #pragma unroll
            for (int r = 0; r < 4; ++r) {
                sc[(quad * 4 + r) * SC_STRIDE + lanelo]      = (bf16_t)s[2][r];
                sc[(quad * 4 + r) * SC_STRIDE + 16 + lanelo] = (bf16_t)s[3][r];
            }
            {   // PV ks=1
                const bf16x8 ap = *(const bf16x8*)(sc + lanelo * SC_STRIDE + quad * 8);
                __builtin_amdgcn_s_setprio(1);
                o_[mi][0] = MFMA16(ap, bv10, o_[mi][0]);
                o_[mi][1] = MFMA16(ap, bv11, o_[mi][1]);
                __builtin_amdgcn_s_setprio(0);
            }
        }
    }
    __syncthreads();   // all vT reads done -> region becomes attn_out

    // attn_out write (C-layout), rows = tokens, stride 200
    #pragma unroll
    for (int mi = 0; mi < 4; ++mi)
        #pragma unroll
        for (int r = 0; r < 4; ++r) {
            const int row = quad * 4 + r + 16 * mi;
            region[row * REG_STRIDE + h * 32 + lanelo]      = (bf16_t)(o_[mi][0][r]);
            region[row * REG_STRIDE + h * 32 + 16 + lanelo] = (bf16_t)(o_[mi][1][r]);
        }
    __syncthreads();

    // ---- phase 3: proj GEMM + bias -> f32 LDS (two 32-token halves) -> full-line
    //      cooperative pixel writes (48 float4 per pixel, contiguous 768 B) ----
    {
        const bf16_t* wb = wbuf + WPROJ_OFF + (wave * 32) * 192;
        f32x4 acc[4][2] = {};
        gemm64x32(xa, wb + lanelo * 192 + quad * 8, wb + (16 + lanelo) * 192 + quad * 8, acc);
        const int o0 = wave * 32 + lanelo;
        const float pb0 = proj_b[o0];
        const float pb1 = proj_b[o0 + 16];
        float* freg = (float*)smem;             // f32 [32][FSTRIDE] view of region
        __syncthreads();                        // all attn-region A-frag reads done
        #pragma unroll
        for (int half = 0; half < 2; ++half) {
            #pragma unroll
            for (int mi = 0; mi < 2; ++mi) {
                const int ami = half * 2 + mi;
                #pragma unroll
                for (int r = 0; r < 4; ++r) {
                    const int row = quad * 4 + r + 16 * mi;   // buffer row = token - 32*half
                    freg[row * FSTRIDE + o0]      = acc[ami][0][r] + pb0;
                    freg[row * FSTRIDE + o0 + 16] = acc[ami][1][r] + pb1;
                }
            }
            __syncthreads();
            const int lim = half ? 816 : 1536;  // (17 or 32 pixels) * 48 float4
            for (int idx = tid; idx < lim; idx += 384) {
                const int t  = idx / 48;
                const int cc = (idx - t * 48) * 4;
                const int tok = half * 32 + t;
                int gr = rowbase + tok / 7;  if (gr >= 112) gr -= 112;
                int gc = colbase + tok % 7;  if (gc >= 112) gc -= 112;
                const float4 v = *(const float4*)(freg + t * FSTRIDE + cc);
                *(float4*)(out + (((long)b * 112 + gr) * 112 + gc) * 192 + cc) = v;
            }
            if (!half) __syncthreads();
        }
    }
}

extern "C" void kernel_launch(void* const* d_in, const int* in_sizes, int n_in,
                              void* d_out, int out_size, void* d_ws, size_t ws_size,
                              hipStream_t stream) {
    const float* x      = (const float*)d_in[0];
    const float* qkv_w  = (const float*)d_in[1];
    const float* qkv_b  = (const float*)d_in[2];
    const float* proj_w = (const float*)d_in[3];
    const float* proj_b = (const float*)d_in[4];
    const float* tbl    = (const float*)d_in[5];
    bf16_t* wbuf = (bf16_t*)d_ws;   // 147456 bf16 = 294,912 B

    convert_w_kernel<<<144, 256, 0, stream>>>(qkv_w, proj_w, wbuf);
    swin_fused_kernel<<<4096, 384, 0, stream>>>(x, wbuf, qkv_b, proj_b, tbl,
                                                (float*)d_out);
}